// Round 18
// baseline (233.275 us; speedup 1.0000x reference)
//
#include <hip/hip_runtime.h>
#include <math.h>

// ---------------------------------------------------------------------------
// AttentionEncoder: B=8, S=2048, D=1024, K=64
// Round 18: R17 config (best measured, 232.6us) + kq_thin converted from the
// old 2-barrier loop to the validated gemm128n single-barrier ring
// (vmcnt(0)+barrier publish, post-barrier stage, lgkm-counted reads, setprio).
// ---------------------------------------------------------------------------

typedef __bf16 bf16_t;
typedef __bf16 bf16x4_t __attribute__((ext_vector_type(4)));
typedef __bf16 bf16x8_t __attribute__((ext_vector_type(8)));
typedef float  f32x4    __attribute__((ext_vector_type(4)));

#define DEV static __device__ __forceinline__

DEV void gll16(const void* g, void* l) {
  __builtin_amdgcn_global_load_lds(
      (const __attribute__((address_space(1))) void*)g,
      (__attribute__((address_space(3))) void*)l, 16, 0, 0);
}

// ---------------------------------------------------------------------------
// gemm128n: 256x128 tile, BK=32, 2-slot ring (48KB) -> 2 blocks/CU.
// MODE 1: VT (bf16, +aux0[row]) ; MODE 4: FF (bf16, relu(+aux0[col]))
// ---------------------------------------------------------------------------
template <int MODE, int MFAST>
__global__ __launch_bounds__(512, 4) void gemm128n(
    const bf16_t* __restrict__ A, const bf16_t* __restrict__ B,
    bf16_t* __restrict__ C, int K, int lda, int ldb, int ldc,
    const float* __restrict__ aux0) {
  const int gx = gridDim.x, gy = gridDim.y;
  const int nwg = gx * gy;
  const int orig = blockIdx.x + gx * blockIdx.y;
  const int lid = (orig & 7) * (nwg >> 3) + (orig >> 3);
  const int bx = MFAST ? (lid / gy) : (lid % gx);
  const int by = MFAST ? (lid % gy) : (lid / gx);
  const int m0 = by * 256, n0 = bx * 128;

  __shared__ bf16_t SM[24576];
#define ASH(s) (&SM[(s) << 13])
#define BSH(s) (&SM[16384 + ((s) << 12)])

  const int tid = threadIdx.x;
  const int wid = tid >> 6, l = tid & 63;
  const int wr = wid >> 1, wc = wid & 1;   // 4M x 2N
  const int lr = l & 15, lh = l >> 4;

  const int sRow = tid >> 2;
  const int sSl = (tid & 3) ^ ((tid >> 3) & 3);
  const bf16_t* Asrc = A + (long)(m0 + sRow) * lda + sSl * 8;
  const bf16_t* Bsrc = B + (long)(n0 + sRow) * ldb + sSl * 8;
  const long aStep = (long)128 * lda;

  const int sw = (lh ^ ((lr >> 1) & 3)) * 8;
  const int aOff = (wr * 64 + lr) * 32 + sw;
  const int bOff = (wc * 64 + lr) * 32 + sw;

  f32x4 acc[4][4] = {};
  const int NT = K >> 5;

  gll16(Asrc, ASH(0) + tid * 8);
  gll16(Asrc + aStep, ASH(0) + 4096 + tid * 8);
  gll16(Bsrc, BSH(0) + tid * 8);

  for (int h = 0; h < NT; ++h) {
    const int s = h & 1;
    asm volatile("s_waitcnt vmcnt(0)" ::: "memory");
    __builtin_amdgcn_sched_barrier(0);
    __builtin_amdgcn_s_barrier();
    if (h + 1 < NT) {
      const bf16_t* a_ = Asrc + (h + 1) * 32;
      const bf16_t* b_ = Bsrc + (h + 1) * 32;
      gll16(a_, ASH(s ^ 1) + tid * 8);
      gll16(a_ + aStep, ASH(s ^ 1) + 4096 + tid * 8);
      gll16(b_, BSH(s ^ 1) + tid * 8);
    }
    bf16x8_t aF[4], bF[4];
#pragma unroll
    for (int m = 0; m < 4; ++m) aF[m] = *(const bf16x8_t*)(ASH(s) + aOff + m * 512);
#pragma unroll
    for (int n = 0; n < 4; ++n) bF[n] = *(const bf16x8_t*)(BSH(s) + bOff + n * 512);
    asm volatile("s_waitcnt lgkmcnt(0)" ::: "memory");
    __builtin_amdgcn_sched_barrier(0);
    __builtin_amdgcn_s_setprio(1);
#pragma unroll
    for (int m = 0; m < 4; ++m)
#pragma unroll
      for (int n = 0; n < 4; ++n)
        acc[m][n] = __builtin_amdgcn_mfma_f32_16x16x32_bf16(aF[m], bF[n], acc[m][n], 0, 0, 0);
    __builtin_amdgcn_s_setprio(0);
  }

  const int rowb = m0 + wr * 64 + lh * 4;
  const int colb = n0 + wc * 64 + lr;
#pragma unroll
  for (int m = 0; m < 4; ++m)
#pragma unroll
    for (int n = 0; n < 4; ++n) {
      const f32x4 v = acc[m][n];
      const int cc = colb + n * 16;
#pragma unroll
      for (int r = 0; r < 4; ++r) {
        const int rr = rowb + m * 16 + r;
        const float val = v[r];
        if constexpr (MODE == 1) {
          C[(long)rr * ldc + cc] = (bf16_t)(val + aux0[rr]);
        } else {
          C[(long)rr * ldc + cc] = (bf16_t)fmaxf(val + aux0[cc], 0.0f);
        }
      }
    }
#undef ASH
#undef BSH
}

// ---------------------------------------------------------------------------
// gemm256p (attn): R12 race-fixed register pipeline.
// ---------------------------------------------------------------------------
template <int MODE>
__global__ __launch_bounds__(512, 2) void gemm256p(
    const bf16_t* __restrict__ A, const bf16_t* __restrict__ B,
    bf16_t* __restrict__ C, int K, int lda, int ldb, int ldc,
    long sAb, long sBb, long sCb, const float* __restrict__ aux0) {
  const int gx = gridDim.x, gy = gridDim.y;
  const int gxy = gx * gy;
  const int nwg = gxy * (int)gridDim.z;
  const int orig = blockIdx.x + gx * blockIdx.y + gxy * blockIdx.z;
  const int lid = (orig & 7) * (nwg >> 3) + (orig >> 3);
  const int bz = lid / gxy;
  const int rem = lid - bz * gxy;
  const int bx = rem % gx;
  const int by = rem / gx;

  A += (long)bz * sAb;
  B += (long)bz * sBb;
  const int m0 = by * 256, n0 = bx * 256;

  __shared__ bf16_t SM[65536];
#define ASH(b, h) (&SM[(((b)*2 + (h)) << 13)])
#define BSH(b, h) (&SM[32768 + (((b)*2 + (h)) << 13)])

  const int tid = threadIdx.x;
  const int wid = tid >> 6, l = tid & 63;
  const int wr = wid >> 2, wc = wid & 3;
  const int lr = l & 15, lh = l >> 4;

  const int sRow = tid >> 2;
  const int sSl = (tid & 3) ^ ((tid >> 3) & 3);
  const bf16_t* Asrc = A + (long)(m0 + sRow) * lda + sSl * 8;
  const bf16_t* Bsrc = B + (long)(n0 + sRow) * ldb + sSl * 8;
  const long aStep = (long)128 * lda, bStep = (long)128 * ldb;

#define STAGE_A(b, h, kt) do { \
    const bf16_t* s_ = Asrc + (kt) * 64 + (h) * 32; \
    gll16(s_,         ASH(b, h) + tid * 8); \
    gll16(s_ + aStep, ASH(b, h) + 4096 + tid * 8); } while (0)
#define STAGE_B(b, h, kt) do { \
    const bf16_t* s_ = Bsrc + (kt) * 64 + (h) * 32; \
    gll16(s_,         BSH(b, h) + tid * 8); \
    gll16(s_ + bStep, BSH(b, h) + 4096 + tid * 8); } while (0)

  const int sw = (lh ^ ((lr >> 1) & 3)) * 8;
  const int aOff = (wr * 128 + lr) * 32 + sw;
  const int bOff = (wc * 64 + lr) * 32 + sw;

  f32x4 acc[8][4] = {};
  const int NT = K >> 6;

#define LGKM(n) do { \
    asm volatile("s_waitcnt lgkmcnt(" #n ")" ::: "memory"); \
    __builtin_amdgcn_sched_barrier(0); } while (0)
#define MFMA16(AS, BS, mo) do { \
    __builtin_amdgcn_s_setprio(1); \
    _Pragma("unroll") for (int m = 0; m < 4; ++m) \
    _Pragma("unroll") for (int n = 0; n < 4; ++n) \
      acc[m + (mo)][n] = __builtin_amdgcn_mfma_f32_16x16x32_bf16(AS[m], BS[n], acc[m + (mo)][n], 0, 0, 0); \
    __builtin_amdgcn_s_setprio(0); } while (0)

  STAGE_A(0, 0, 0); STAGE_B(0, 0, 0); STAGE_A(0, 1, 0); STAGE_B(0, 1, 0);
  asm volatile("s_waitcnt vmcnt(4)" ::: "memory");
  __builtin_amdgcn_s_barrier();

  bf16x8_t aA[4], aB[4], bA[4], bB[4];
#pragma unroll
  for (int n = 0; n < 4; ++n) bA[n] = *(const bf16x8_t*)(BSH(0, 0) + bOff + n * 512);
#pragma unroll
  for (int m = 0; m < 4; ++m) aA[m] = *(const bf16x8_t*)(ASH(0, 0) + aOff + m * 512);

  for (int t = 0; t < NT; ++t) {
    const int p = t & 1, q = p ^ 1;
    const bool pf = (t + 1 < NT);

#pragma unroll
    for (int m = 0; m < 4; ++m) aB[m] = *(const bf16x8_t*)(ASH(p, 0) + aOff + (m + 4) * 512);
    if (pf) STAGE_A(q, 0, t + 1);
    LGKM(4);
    MFMA16(aA, bA, 0);

    if (pf) {
      asm volatile("s_waitcnt vmcnt(2)" ::: "memory");
    } else {
      asm volatile("s_waitcnt vmcnt(0)" ::: "memory");
    }
    __builtin_amdgcn_sched_barrier(0);
    __builtin_amdgcn_s_barrier();
#pragma unroll
    for (int m = 0; m < 4; ++m) aA[m] = *(const bf16x8_t*)(ASH(p, 1) + aOff + m * 512);
#pragma unroll
    for (int n = 0; n < 4; ++n) bB[n] = *(const bf16x8_t*)(BSH(p, 1) + bOff + n * 512);
    if (pf) STAGE_B(q, 0, t + 1);
    LGKM(8);
    MFMA16(aB, bA, 4);

#pragma unroll
    for (int m = 0; m < 4; ++m) aB[m] = *(const bf16x8_t*)(ASH(p, 1) + aOff + (m + 4) * 512);
    if (pf) STAGE_A(q, 1, t + 1);
    LGKM(4);
    MFMA16(aA, bB, 0);

    if (pf) STAGE_B(q, 1, t + 1);
    asm volatile("s_waitcnt lgkmcnt(0)" ::: "memory");
    if (pf) {
      asm volatile("s_waitcnt vmcnt(4)" ::: "memory");
    }
    __builtin_amdgcn_sched_barrier(0);
    __builtin_amdgcn_s_barrier();
    if (pf) {
#pragma unroll
      for (int n = 0; n < 4; ++n) bA[n] = *(const bf16x8_t*)(BSH(q, 0) + bOff + n * 512);
#pragma unroll
      for (int m = 0; m < 4; ++m) aA[m] = *(const bf16x8_t*)(ASH(q, 0) + aOff + m * 512);
    }
    __builtin_amdgcn_sched_barrier(0);
    MFMA16(aB, bB, 4);
  }
#undef STAGE_A
#undef STAGE_B
#undef LGKM
#undef MFMA16

  bf16_t* Cb = C + (long)bz * sCb;
  const int rowb = m0 + wr * 128 + lh * 4;
  const int colb = n0 + wc * 64 + lr;
#pragma unroll
  for (int m = 0; m < 8; ++m)
#pragma unroll
    for (int n = 0; n < 4; ++n) {
      const f32x4 v = acc[m][n];
      const int cc = colb + n * 16;
#pragma unroll
      for (int r = 0; r < 4; ++r) {
        const int rr = rowb + m * 16 + r;
        Cb[(long)rr * ldc + cc] = (bf16_t)v[r];
      }
    }
#undef ASH
#undef BSH
}

// ---------------------------------------------------------------------------
// scores128 (R13): single K-pass, sigmoid, LDS-bounce coalesced write.
// ---------------------------------------------------------------------------
__global__ __launch_bounds__(256) void scores128(
    const bf16_t* __restrict__ kq, bf16_t* __restrict__ C,
    const float* __restrict__ biases) {
  const int orig = blockIdx.x + 16 * blockIdx.y + 256 * blockIdx.z;
  const int lid = (orig & 7) * 256 + (orig >> 3);
  const int bz = lid >> 8;
  const int rem = lid & 255;
  const int bx = rem & 15, by = rem >> 4;

  const bf16_t* A = kq + (long)bz * 2048 * 128;
  const bf16_t* B = A + 64;
  const float* a0 = biases + (long)bz * 2048;
  const int m0 = by * 128, n0 = bx * 128;

  __shared__ bf16_t SM[16384];
#define ASH(h) (&SM[(h) << 12])
#define BSH(h) (&SM[8192 + ((h) << 12)])

  const int tid = threadIdx.x;
  const int w = tid >> 6, l = tid & 63;
  const int wr = w >> 1, wc = w & 1;
  const int lr = l & 15, lh = l >> 4;

  const int sRow = tid >> 2;
  const int sSl = ((tid & 3) ^ ((tid >> 3) & 3)) * 8;
  const bf16_t* As = A + (long)(m0 + sRow) * 128 + sSl;
  const bf16_t* Bs = B + (long)(n0 + sRow) * 128 + sSl;
#pragma unroll
  for (int h = 0; h < 2; ++h) {
    gll16(As + h * 32, ASH(h) + tid * 8);
    gll16(As + h * 32 + 64 * 128, ASH(h) + 2048 + tid * 8);
    gll16(Bs + h * 32, BSH(h) + tid * 8);
    gll16(Bs + h * 32 + 64 * 128, BSH(h) + 2048 + tid * 8);
  }
  asm volatile("s_waitcnt vmcnt(0)" ::: "memory");
  __builtin_amdgcn_s_barrier();

  const int sw = (lh ^ ((lr >> 1) & 3)) * 8;
  const int aOff = (wr * 64 + lr) * 32 + sw;
  const int bOff = (wc * 64 + lr) * 32 + sw;

  f32x4 acc[4][4] = {};
#pragma unroll
  for (int h = 0; h < 2; ++h) {
    bf16x8_t aF[4], bF[4];
#pragma unroll
    for (int m = 0; m < 4; ++m) aF[m] = *(const bf16x8_t*)(ASH(h) + aOff + m * 512);
#pragma unroll
    for (int n = 0; n < 4; ++n) bF[n] = *(const bf16x8_t*)(BSH(h) + bOff + n * 512);
#pragma unroll
    for (int m = 0; m < 4; ++m)
#pragma unroll
      for (int n = 0; n < 4; ++n)
        acc[m][n] = __builtin_amdgcn_mfma_f32_16x16x32_bf16(aF[m], bF[n], acc[m][n], 0, 0, 0);
  }

  __builtin_amdgcn_s_barrier();
  {
    const int rowb = (wr << 6) + (lh << 2);
    const int colb = (wc << 6) + lr;
#pragma unroll
    for (int m = 0; m < 4; ++m)
#pragma unroll
      for (int n = 0; n < 4; ++n) {
        const f32x4 v = acc[m][n];
        const int cl = colb + (n << 4);
#pragma unroll
        for (int r = 0; r < 4; ++r) {
          const int rl = rowb + (m << 4) + r;
          const float zz = v[r] + a0[m0 + rl];
          SM[rl * 128 + (cl ^ (lh << 4))] =
              (bf16_t)__builtin_amdgcn_rcpf(1.0f + __expf(-zz));
        }
      }
    __syncthreads();
    bf16_t* Cb = C + (long)bz * 2048 * 2048;
    const int chunk = tid & 15, rsub = tid >> 4;
#pragma unroll
    for (int pp = 0; pp < 8; ++pp) {
      const int rl = pp * 16 + rsub;
      const int sc = chunk ^ (((rl >> 2) & 3) << 1);
      const bf16x8_t vv = *(const bf16x8_t*)&SM[rl * 128 + sc * 8];
      *(bf16x8_t*)&Cb[(long)(m0 + rl) * 2048 + n0 + chunk * 8] = vv;
    }
  }
#undef ASH
#undef BSH
}

// ---------------------------------------------------------------------------
// kq_thin: [16384][128] = x_bf @ Wkqt^T, 64x128 tile, 256 blocks.
// R18: single-barrier ring (gemm128n pattern): vmcnt(0)+barrier publish,
// post-barrier stage of next slot, lgkm(0) before MFMA, setprio wrap.
// ---------------------------------------------------------------------------
__global__ __launch_bounds__(256) void kq_thin(
    const bf16_t* __restrict__ A, const bf16_t* __restrict__ B,
    bf16_t* __restrict__ C,
    const float* __restrict__ bk, const float* __restrict__ bq) {
  const int m0 = blockIdx.x * 64;

  __shared__ bf16_t SM[12288];
#define ASH(b) (&SM[(b) << 11])
#define BSH(b) (&SM[4096 + ((b) << 12)])

  const int tid = threadIdx.x;
  const int w = tid >> 6, l = tid & 63;
  const int lr = l & 15, lh = l >> 4;

  const int sRow = tid >> 2;
  const int sSl = (tid & 3) ^ ((tid >> 3) & 3);
  const bf16_t* Asrc = A + (long)(m0 + sRow) * 1024 + sSl * 8;
  const bf16_t* Bsrc0 = B + (long)sRow * 1024 + sSl * 8;
  const bf16_t* Bsrc1 = B + (long)(64 + sRow) * 1024 + sSl * 8;

  const int sw = (lh ^ ((lr >> 1) & 3)) * 8;
  const int aOff = (w * 16 + lr) * 32 + sw;

  f32x4 acc[8] = {};

  auto stage = [&](int buf, int k0) {
    gll16(Asrc + k0, ASH(buf) + tid * 8);
    gll16(Bsrc0 + k0, BSH(buf) + tid * 8);
    gll16(Bsrc1 + k0, BSH(buf) + 2048 + tid * 8);
  };

  stage(0, 0);
  for (int h = 0; h < 32; ++h) {
    const int s = h & 1;
    asm volatile("s_waitcnt vmcnt(0)" ::: "memory");
    __builtin_amdgcn_sched_barrier(0);
    __builtin_amdgcn_s_barrier();
    if (h + 1 < 32) stage(s ^ 1, (h + 1) * 32);

    const bf16x8_t aF = *(const bf16x8_t*)(ASH(s) + aOff);
    bf16x8_t bF[8];
#pragma unroll
    for (int j = 0; j < 8; ++j)
      bF[j] = *(const bf16x8_t*)(BSH(s) + (j * 16 + lr) * 32 + sw);
    asm volatile("s_waitcnt lgkmcnt(0)" ::: "memory");
    __builtin_amdgcn_sched_barrier(0);
    __builtin_amdgcn_s_setprio(1);
#pragma unroll
    for (int j = 0; j < 8; ++j)
      acc[j] = __builtin_amdgcn_mfma_f32_16x16x32_bf16(aF, bF[j], acc[j], 0, 0, 0);
    __builtin_amdgcn_s_setprio(0);
  }

  {
#pragma unroll
    for (int j = 0; j < 8; ++j) {
      const f32x4 v = acc[j];
      const int cl = j * 16 + lr;
      const float b = (cl < 64) ? bk[cl] : bq[cl - 64];
      const float s = (cl < 64) ? 0.125f : 1.0f;
#pragma unroll
      for (int r = 0; r < 4; ++r) {
        const int rl = w * 16 + lh * 4 + r;
        SM[rl * 128 + (cl ^ (lh << 4))] = (bf16_t)((v[r] + b) * s);
      }
    }
    __syncthreads();
    const int chunk = tid & 15, rsub = tid >> 4;
#pragma unroll
    for (int pp = 0; pp < 4; ++pp) {
      const int rl = pp * 16 + rsub;
      const int sc = chunk ^ (((rl >> 2) & 3) << 1);
      const bf16x8_t vv = *(const bf16x8_t*)&SM[rl * 128 + sc * 8];
      *(bf16x8_t*)&C[(long)(m0 + rl) * 128 + chunk * 8] = vv;
    }
  }
#undef ASH
#undef BSH
}

// ---------------------------------------------------------------------------
// prep: blocks <4096 = cast x->bf16 + row-dot bias; blocks >=4096 = weight
// transposes (Wv, W1, Wk, Wq).
// ---------------------------------------------------------------------------
__global__ __launch_bounds__(256) void prep(
    const float* __restrict__ x, const float* __restrict__ Wb,
    const float* __restrict__ bb, bf16_t* __restrict__ x_bf,
    float* __restrict__ biases,
    const float* __restrict__ Wk, const float* __restrict__ Wq,
    const float* __restrict__ Wv, const float* __restrict__ W1,
    bf16_t* __restrict__ Wkqt, bf16_t* __restrict__ Wvt,
    bf16_t* __restrict__ W1t) {
  __shared__ float t[32][33];
  if (blockIdx.x < 4096) {
    const int r = blockIdx.x * 4 + (threadIdx.x >> 6);
    const int l = threadIdx.x & 63;
    const float* xr = x + (long)r * 1024;
    bf16_t* orow = x_bf + (long)r * 1024;
    float s = 0.f;
#pragma unroll
    for (int i = 0; i < 4; ++i) {
      const int off = l * 4 + i * 256;
      const float4 v = *(const float4*)(xr + off);
      const float4 w = *(const float4*)(Wb + off);
      s += v.x * w.x + v.y * w.y + v.z * w.z + v.w * w.w;
      bf16x4_t o;
      o[0] = (bf16_t)v.x; o[1] = (bf16_t)v.y; o[2] = (bf16_t)v.z; o[3] = (bf16_t)v.w;
      *(bf16x4_t*)(orow + off) = o;
    }
#pragma unroll
    for (int off = 1; off < 64; off <<= 1) s += __shfl_xor(s, off);
    if (l == 0) biases[r] = s + bb[0];
    return;
  }
  int b = blockIdx.x - 4096;
  const float* in;
  bf16_t* out;
  int R = 1024, C, c0, r0;
  if (b < 1024) {
    in = Wv; out = Wvt; C = 1024;
    c0 = (b & 31) * 32; r0 = (b >> 5) * 32;
  } else if (b < 2048) {
    b -= 1024; in = W1; out = W1t; C = 1024;
    c0 = (b & 31) * 32; r0 = (b >> 5) * 32;
  } else if (b < 2112) {
    b -= 2048; in = Wk; out = Wkqt; C = 64;
    c0 = (b & 1) * 32; r0 = (b >> 1) * 32;
  } else {
    b -= 2112; in = Wq; out = Wkqt + 64 * 1024; C = 64;
    c0 = (b & 1) * 32; r0 = (b >> 1) * 32;
  }
  const int tx = threadIdx.x & 31, ty = threadIdx.x >> 5;
#pragma unroll
  for (int i = 0; i < 4; ++i) {
    const int rl = ty * 4 + i;
    t[rl][tx] = in[(long)(r0 + rl) * C + c0 + tx];
  }
  __syncthreads();
#pragma unroll
  for (int i = 0; i < 4; ++i) {
    const int rl = ty * 4 + i;
    out[(long)(c0 + rl) * R + r0 + tx] = (bf16_t)t[tx][rl];
  }
}

// wave-per-row LayerNorm: res = bf16(LN(x+attn)*g+be)
__global__ __launch_bounds__(256) void ln1_kernel(
    const bf16_t* __restrict__ x, const bf16_t* __restrict__ attn,
    const float* __restrict__ g, const float* __restrict__ be,
    bf16_t* __restrict__ res) {
  const int w = threadIdx.x >> 6, l = threadIdx.x & 63;
  const long r = (long)blockIdx.x * 4 + w;
  const bf16_t* xr = x + r * 1024;
  const bf16_t* ar = attn + r * 1024;
  float y[16];
  float s = 0.f, ss = 0.f;
#pragma unroll
  for (int h = 0; h < 2; ++h) {
    const int base = h * 512 + l * 8;
    const bf16x8_t xv = *(const bf16x8_t*)(xr + base);
    const bf16x8_t av = *(const bf16x8_t*)(ar + base);
#pragma unroll
    for (int j = 0; j < 8; ++j) {
      const float yy = (float)xv[j] + (float)av[j];
      y[h * 8 + j] = yy;
      s += yy; ss += yy * yy;
    }
  }
#pragma unroll
  for (int off = 1; off < 64; off <<= 1) {
    s += __shfl_xor(s, off);
    ss += __shfl_xor(ss, off);
  }
  const float mean = s * (1.0f / 1024.0f);
  const float rs = rsqrtf(ss * (1.0f / 1024.0f) - mean * mean + 1e-5f);
  bf16_t* orow = res + r * 1024;
#pragma unroll
  for (int h = 0; h < 2; ++h) {
    const int base = h * 512 + l * 8;
    bf16x8_t o;
#pragma unroll
    for (int j = 0; j < 8; ++j)
      o[j] = (bf16_t)((y[h * 8 + j] - mean) * rs * g[base + j] + be[base + j]);
    *(bf16x8_t*)(orow + base) = o;
  }
}

// wave-per-row: out = LN(res + h), fp32 out
__global__ __launch_bounds__(256) void ln2_kernel(
    const bf16_t* __restrict__ res, const bf16_t* __restrict__ hh,
    float* __restrict__ out) {
  const int w = threadIdx.x >> 6, l = threadIdx.x & 63;
  const long r = (long)blockIdx.x * 4 + w;
  const bf16_t* rr = res + r * 1024;
  const bf16_t* hr = hh + r * 1024;
  float y[16];
  float s = 0.f, ss = 0.f;
#pragma unroll
  for (int h = 0; h < 2; ++h) {
    const int base = h * 512 + l * 8;
    const bf16x8_t rv = *(const bf16x8_t*)(rr + base);
    const bf16x8_t hv = *(const bf16x8_t*)(hr + base);
#pragma unroll
    for (int j = 0; j < 8; ++j) {
      const float yy = (float)rv[j] + (float)hv[j];
      y[h * 8 + j] = yy;
      s += yy; ss += yy * yy;
    }
  }
#pragma unroll
  for (int off = 1; off < 64; off <<= 1) {
    s += __shfl_xor(s, off);
    ss += __shfl_xor(ss, off);
  }
  const float mean = s * (1.0f / 1024.0f);
  const float rs = rsqrtf(ss * (1.0f / 1024.0f) - mean * mean + 1e-5f);
  float* orow = out + r * 1024;
#pragma unroll
  for (int h = 0; h < 2; ++h) {
    const int base = h * 512 + l * 8;
    float4 o1, o2;
    o1.x = (y[h * 8 + 0] - mean) * rs; o1.y = (y[h * 8 + 1] - mean) * rs;
    o1.z = (y[h * 8 + 2] - mean) * rs; o1.w = (y[h * 8 + 3] - mean) * rs;
    o2.x = (y[h * 8 + 4] - mean) * rs; o2.y = (y[h * 8 + 5] - mean) * rs;
    o2.z = (y[h * 8 + 6] - mean) * rs; o2.w = (y[h * 8 + 7] - mean) * rs;
    *(float4*)(orow + base) = o1;
    *(float4*)(orow + base + 4) = o2;
  }
}

// ---------------------------------------------------------------------------
extern "C" void kernel_launch(void* const* d_in, const int* in_sizes, int n_in,
                              void* d_out, int out_size, void* d_ws, size_t ws_size,
                              hipStream_t stream) {
  const float* x   = (const float*)d_in[0];
  const float* Wk  = (const float*)d_in[1];
  const float* bk  = (const float*)d_in[2];
  const float* Wq  = (const float*)d_in[3];
  const float* bq  = (const float*)d_in[4];
  const float* Wv  = (const float*)d_in[5];
  const float* bv  = (const float*)d_in[6];
  const float* Wb  = (const float*)d_in[7];
  const float* bb  = (const float*)d_in[8];
  const float* W1  = (const float*)d_in[9];
  const float* b1  = (const float*)d_in[10];
  const float* g1  = (const float*)d_in[11];
  const float* be1 = (const float*)d_in[12];
  float* out = (float*)d_out;

  char* ws = (char*)d_ws;
  bf16_t* x_bf    = (bf16_t*)(ws + 0);           //  32 MB  [16384][1024]
  bf16_t* vt_bf   = (bf16_t*)(ws + 33554432);    //  32 MB  V^T [1024][16384]
  bf16_t* kq_bf   = (bf16_t*)(ws + 67108864);    //   4 MB  [16384][128]
  bf16_t* Wkqt    = (bf16_t*)(ws + 71303168);    // 256 KB  [128][1024]
  bf16_t* Wvt     = (bf16_t*)(ws + 71565312);    //   2 MB
  bf16_t* W1t     = (bf16_t*)(ws + 73662464);    //   2 MB
  float*  biases  = (float*) (ws + 75759616);    //  64 KB
  bf16_t* scores  = (bf16_t*)(ws + 75825152);    //  64 MB  [8][2048][2048]
  bf16_t* attn_bf = (bf16_t*)(ws + 142934016);   //  32 MB  [8][2048][1024]
  bf16_t* res_bf  = (bf16_t*)(ws + 176488448);   //  32 MB
  bf16_t* h_bf    = attn_bf;                     // alias: attn dead after ln1

  // cast+bias+transposes in one launch
  prep<<<6272, 256, 0, stream>>>(x, Wb, bb, x_bf, biases,
                                 Wk, Wq, Wv, W1, Wkqt, Wvt, W1t);

  // keys|queries: [16384][128]
  kq_thin<<<256, 256, 0, stream>>>(x_bf, Wkqt, kq_bf, bk, bq);

  // V^T = Wv^T @ x^T (+bv row bias)
  gemm128n<1, 1><<<dim3(128, 4), 512, 0, stream>>>(
      Wvt, x_bf, vt_bf, 1024, 1024, 1024, 16384, bv);

  // scores = sigmoid(keys.queries^T + bias_i)
  scores128<<<dim3(16, 16, 8), 256, 0, stream>>>(kq_bf, scores, biases);

  // attn = scores @ V
  gemm256p<3><<<dim3(4, 8, 8), 512, 0, stream>>>(
      scores, vt_bf, attn_bf, 2048, 2048, 16384, 1024,
      2048L * 2048, 2048, 2048L * 1024, nullptr);

  // res = bf16(LN(x+attn)*g1+be1)
  ln1_kernel<<<4096, 256, 0, stream>>>(x_bf, attn_bf, g1, be1, res_bf);

  // h = relu(res @ W1 + b1)
  gemm128n<4, 0><<<dim3(8, 64), 512, 0, stream>>>(
      res_bf, W1t, h_bf, 1024, 1024, 1024, 1024, b1);

  // out = LN(res + h)
  ln2_kernel<<<4096, 256, 0, stream>>>(res_bf, h_bf, out);
}

// Round 19
// 230.634 us; speedup vs baseline: 1.0115x; 1.0115x over previous
//
#include <hip/hip_runtime.h>
#include <math.h>

// ---------------------------------------------------------------------------
// AttentionEncoder: B=8, S=2048, D=1024, K=64
// Round 19: VT and KQ merged into ONE launch (they're independent; the
// sequential stream was serializing them). kq upgraded to 128-row/512-thread
// tile (128 blocks) appended after VT's 512 blocks. Everything else = R17
// best config (232.6us): prep, scores128, gemm256p attn, ln1, gemm128n FF, ln2.
// ---------------------------------------------------------------------------

typedef __bf16 bf16_t;
typedef __bf16 bf16x4_t __attribute__((ext_vector_type(4)));
typedef __bf16 bf16x8_t __attribute__((ext_vector_type(8)));
typedef float  f32x4    __attribute__((ext_vector_type(4)));

#define DEV static __device__ __forceinline__

DEV void gll16(const void* g, void* l) {
  __builtin_amdgcn_global_load_lds(
      (const __attribute__((address_space(1))) void*)g,
      (__attribute__((address_space(3))) void*)l, 16, 0, 0);
}

// ---------------------------------------------------------------------------
// vt_kq: blocks 0..511 = VT (256x128 tile, 2-slot ring, as gemm128n MODE 1);
// blocks 512..639 = KQ (128x128 tile, K=1024, bias+scale epilogue).
// 48KB LDS both roles; 512 threads.
// ---------------------------------------------------------------------------
__global__ __launch_bounds__(512, 4) void vt_kq(
    const bf16_t* __restrict__ Wvt, const bf16_t* __restrict__ x_bf,
    bf16_t* __restrict__ vt, const float* __restrict__ bv,
    const bf16_t* __restrict__ Wkqt, bf16_t* __restrict__ kqO,
    const float* __restrict__ bk, const float* __restrict__ bq) {
  __shared__ bf16_t SM[24576];
  const int tid = threadIdx.x;
  const int wid = tid >> 6, l = tid & 63;
  const int lr = l & 15, lh = l >> 4;
  const int sw = (lh ^ ((lr >> 1) & 3)) * 8;

  if (blockIdx.x < 512) {
    // ================= VT role: vt = Wvt @ x_bf^T (+bv[row]) ==============
#define ASH(s) (&SM[(s) << 13])
#define BSH(s) (&SM[16384 + ((s) << 12)])
    const int nwg = 512;
    const int orig = blockIdx.x;
    const int lid = (orig & 7) * (nwg >> 3) + (orig >> 3);
    const int bx = lid / 4;          // MFAST: 128 n-blocks
    const int by = lid % 4;          // 4 m-blocks
    const int m0 = by * 256, n0 = bx * 128;
    const int lda = 1024, ldb = 1024, ldc = 16384;

    const int wr = wid >> 1, wc = wid & 1;
    const int sRow = tid >> 2;
    const int sSl = (tid & 3) ^ ((tid >> 3) & 3);
    const bf16_t* Asrc = Wvt + (long)(m0 + sRow) * lda + sSl * 8;
    const bf16_t* Bsrc = x_bf + (long)(n0 + sRow) * ldb + sSl * 8;
    const long aStep = (long)128 * lda;

    const int aOff = (wr * 64 + lr) * 32 + sw;
    const int bOff = (wc * 64 + lr) * 32 + sw;

    f32x4 acc[4][4] = {};

    gll16(Asrc, ASH(0) + tid * 8);
    gll16(Asrc + aStep, ASH(0) + 4096 + tid * 8);
    gll16(Bsrc, BSH(0) + tid * 8);

    for (int h = 0; h < 32; ++h) {
      const int s = h & 1;
      asm volatile("s_waitcnt vmcnt(0)" ::: "memory");
      __builtin_amdgcn_sched_barrier(0);
      __builtin_amdgcn_s_barrier();
      if (h + 1 < 32) {
        const bf16_t* a_ = Asrc + (h + 1) * 32;
        const bf16_t* b_ = Bsrc + (h + 1) * 32;
        gll16(a_, ASH(s ^ 1) + tid * 8);
        gll16(a_ + aStep, ASH(s ^ 1) + 4096 + tid * 8);
        gll16(b_, BSH(s ^ 1) + tid * 8);
      }
      bf16x8_t aF[4], bF[4];
#pragma unroll
      for (int m = 0; m < 4; ++m) aF[m] = *(const bf16x8_t*)(ASH(s) + aOff + m * 512);
#pragma unroll
      for (int n = 0; n < 4; ++n) bF[n] = *(const bf16x8_t*)(BSH(s) + bOff + n * 512);
      asm volatile("s_waitcnt lgkmcnt(0)" ::: "memory");
      __builtin_amdgcn_sched_barrier(0);
      __builtin_amdgcn_s_setprio(1);
#pragma unroll
      for (int m = 0; m < 4; ++m)
#pragma unroll
        for (int n = 0; n < 4; ++n)
          acc[m][n] = __builtin_amdgcn_mfma_f32_16x16x32_bf16(aF[m], bF[n], acc[m][n], 0, 0, 0);
      __builtin_amdgcn_s_setprio(0);
    }

    const int rowb = m0 + wr * 64 + lh * 4;
    const int colb = n0 + wc * 64 + lr;
#pragma unroll
    for (int m = 0; m < 4; ++m)
#pragma unroll
      for (int n = 0; n < 4; ++n) {
        const f32x4 v = acc[m][n];
        const int cc = colb + n * 16;
#pragma unroll
        for (int r = 0; r < 4; ++r) {
          const int rr = rowb + m * 16 + r;
          vt[(long)rr * ldc + cc] = (bf16_t)(v[r] + bv[rr]);
        }
      }
#undef ASH
#undef BSH
  } else {
    // ================= KQ role: kq = x_bf @ Wkqt^T, 128x128 tile ==========
#define ASH(s) (&SM[(s) << 12])
#define BSH(s) (&SM[8192 + ((s) << 12)])
    const int m0 = (blockIdx.x - 512) * 128;

    const int sRow = tid >> 2;                      // 0..127
    const int sSl = (tid & 3) ^ ((tid >> 3) & 3);
    const bf16_t* Asrc = x_bf + (long)(m0 + sRow) * 1024 + sSl * 8;
    const bf16_t* Bsrc = Wkqt + (long)sRow * 1024 + sSl * 8;

    const int aOff = (wid * 16 + lr) * 32 + sw;     // wave wid owns 16 rows

    f32x4 acc[8] = {};

    gll16(Asrc, ASH(0) + tid * 8);
    gll16(Bsrc, BSH(0) + tid * 8);

    for (int h = 0; h < 32; ++h) {
      const int s = h & 1;
      asm volatile("s_waitcnt vmcnt(0)" ::: "memory");
      __builtin_amdgcn_sched_barrier(0);
      __builtin_amdgcn_s_barrier();
      if (h + 1 < 32) {
        gll16(Asrc + (h + 1) * 32, ASH(s ^ 1) + tid * 8);
        gll16(Bsrc + (h + 1) * 32, BSH(s ^ 1) + tid * 8);
      }
      const bf16x8_t aF = *(const bf16x8_t*)(ASH(s) + aOff);
      bf16x8_t bF[8];
#pragma unroll
      for (int j = 0; j < 8; ++j)
        bF[j] = *(const bf16x8_t*)(BSH(s) + (j * 16 + lr) * 32 + sw);
      asm volatile("s_waitcnt lgkmcnt(0)" ::: "memory");
      __builtin_amdgcn_sched_barrier(0);
      __builtin_amdgcn_s_setprio(1);
#pragma unroll
      for (int j = 0; j < 8; ++j)
        acc[j] = __builtin_amdgcn_mfma_f32_16x16x32_bf16(aF, bF[j], acc[j], 0, 0, 0);
      __builtin_amdgcn_s_setprio(0);
    }

    // epilogue: bias+scale -> 128x128 bf16 LDS bounce -> coalesced stores
    __builtin_amdgcn_s_barrier();
#pragma unroll
    for (int j = 0; j < 8; ++j) {
      const f32x4 v = acc[j];
      const int cl = j * 16 + lr;
      const float b = (cl < 64) ? bk[cl] : bq[cl - 64];
      const float sc = (cl < 64) ? 0.125f : 1.0f;
#pragma unroll
      for (int r = 0; r < 4; ++r) {
        const int rl = wid * 16 + lh * 4 + r;
        SM[rl * 128 + (cl ^ (lh << 4))] = (bf16_t)((v[r] + b) * sc);
      }
    }
    __builtin_amdgcn_s_barrier();
    const int chunk = tid & 15, rsub = tid >> 4;    // rsub 0..31
#pragma unroll
    for (int pp = 0; pp < 4; ++pp) {
      const int rl = pp * 32 + rsub;
      const int sc = chunk ^ (((rl >> 2) & 3) << 1);
      const bf16x8_t vv = *(const bf16x8_t*)&SM[rl * 128 + sc * 8];
      *(bf16x8_t*)&kqO[(long)(m0 + rl) * 128 + chunk * 8] = vv;
    }
#undef ASH
#undef BSH
  }
}

// ---------------------------------------------------------------------------
// gemm128n (FF): 256x128 tile, BK=32, 2-slot ring (48KB) -> 2 blocks/CU.
// MODE 4: FF (bf16, relu(+aux0[col]))
// ---------------------------------------------------------------------------
template <int MODE, int MFAST>
__global__ __launch_bounds__(512, 4) void gemm128n(
    const bf16_t* __restrict__ A, const bf16_t* __restrict__ B,
    bf16_t* __restrict__ C, int K, int lda, int ldb, int ldc,
    const float* __restrict__ aux0) {
  const int gx = gridDim.x, gy = gridDim.y;
  const int nwg = gx * gy;
  const int orig = blockIdx.x + gx * blockIdx.y;
  const int lid = (orig & 7) * (nwg >> 3) + (orig >> 3);
  const int bx = MFAST ? (lid / gy) : (lid % gx);
  const int by = MFAST ? (lid % gy) : (lid / gx);
  const int m0 = by * 256, n0 = bx * 128;

  __shared__ bf16_t SM[24576];
#define ASH(s) (&SM[(s) << 13])
#define BSH(s) (&SM[16384 + ((s) << 12)])

  const int tid = threadIdx.x;
  const int wid = tid >> 6, l = tid & 63;
  const int wr = wid >> 1, wc = wid & 1;
  const int lr = l & 15, lh = l >> 4;

  const int sRow = tid >> 2;
  const int sSl = (tid & 3) ^ ((tid >> 3) & 3);
  const bf16_t* Asrc = A + (long)(m0 + sRow) * lda + sSl * 8;
  const bf16_t* Bsrc = B + (long)(n0 + sRow) * ldb + sSl * 8;
  const long aStep = (long)128 * lda;

  const int sw = (lh ^ ((lr >> 1) & 3)) * 8;
  const int aOff = (wr * 64 + lr) * 32 + sw;
  const int bOff = (wc * 64 + lr) * 32 + sw;

  f32x4 acc[4][4] = {};
  const int NT = K >> 5;

  gll16(Asrc, ASH(0) + tid * 8);
  gll16(Asrc + aStep, ASH(0) + 4096 + tid * 8);
  gll16(Bsrc, BSH(0) + tid * 8);

  for (int h = 0; h < NT; ++h) {
    const int s = h & 1;
    asm volatile("s_waitcnt vmcnt(0)" ::: "memory");
    __builtin_amdgcn_sched_barrier(0);
    __builtin_amdgcn_s_barrier();
    if (h + 1 < NT) {
      const bf16_t* a_ = Asrc + (h + 1) * 32;
      const bf16_t* b_ = Bsrc + (h + 1) * 32;
      gll16(a_, ASH(s ^ 1) + tid * 8);
      gll16(a_ + aStep, ASH(s ^ 1) + 4096 + tid * 8);
      gll16(b_, BSH(s ^ 1) + tid * 8);
    }
    bf16x8_t aF[4], bF[4];
#pragma unroll
    for (int m = 0; m < 4; ++m) aF[m] = *(const bf16x8_t*)(ASH(s) + aOff + m * 512);
#pragma unroll
    for (int n = 0; n < 4; ++n) bF[n] = *(const bf16x8_t*)(BSH(s) + bOff + n * 512);
    asm volatile("s_waitcnt lgkmcnt(0)" ::: "memory");
    __builtin_amdgcn_sched_barrier(0);
    __builtin_amdgcn_s_setprio(1);
#pragma unroll
    for (int m = 0; m < 4; ++m)
#pragma unroll
      for (int n = 0; n < 4; ++n)
        acc[m][n] = __builtin_amdgcn_mfma_f32_16x16x32_bf16(aF[m], bF[n], acc[m][n], 0, 0, 0);
    __builtin_amdgcn_s_setprio(0);
  }

  const int rowb = m0 + wr * 64 + lh * 4;
  const int colb = n0 + wc * 64 + lr;
#pragma unroll
  for (int m = 0; m < 4; ++m)
#pragma unroll
    for (int n = 0; n < 4; ++n) {
      const f32x4 v = acc[m][n];
      const int cc = colb + n * 16;
#pragma unroll
      for (int r = 0; r < 4; ++r) {
        const int rr = rowb + m * 16 + r;
        const float val = v[r];
        if constexpr (MODE == 1) {
          C[(long)rr * ldc + cc] = (bf16_t)(val + aux0[rr]);
        } else {
          C[(long)rr * ldc + cc] = (bf16_t)fmaxf(val + aux0[cc], 0.0f);
        }
      }
    }
#undef ASH
#undef BSH
}

// ---------------------------------------------------------------------------
// gemm256p (attn): R12 race-fixed register pipeline.
// ---------------------------------------------------------------------------
template <int MODE>
__global__ __launch_bounds__(512, 2) void gemm256p(
    const bf16_t* __restrict__ A, const bf16_t* __restrict__ B,
    bf16_t* __restrict__ C, int K, int lda, int ldb, int ldc,
    long sAb, long sBb, long sCb, const float* __restrict__ aux0) {
  const int gx = gridDim.x, gy = gridDim.y;
  const int gxy = gx * gy;
  const int nwg = gxy * (int)gridDim.z;
  const int orig = blockIdx.x + gx * blockIdx.y + gxy * blockIdx.z;
  const int lid = (orig & 7) * (nwg >> 3) + (orig >> 3);
  const int bz = lid / gxy;
  const int rem = lid - bz * gxy;
  const int bx = rem % gx;
  const int by = rem / gx;

  A += (long)bz * sAb;
  B += (long)bz * sBb;
  const int m0 = by * 256, n0 = bx * 256;

  __shared__ bf16_t SM[65536];
#define ASH(b, h) (&SM[(((b)*2 + (h)) << 13)])
#define BSH(b, h) (&SM[32768 + (((b)*2 + (h)) << 13)])

  const int tid = threadIdx.x;
  const int wid = tid >> 6, l = tid & 63;
  const int wr = wid >> 2, wc = wid & 3;
  const int lr = l & 15, lh = l >> 4;

  const int sRow = tid >> 2;
  const int sSl = (tid & 3) ^ ((tid >> 3) & 3);
  const bf16_t* Asrc = A + (long)(m0 + sRow) * lda + sSl * 8;
  const bf16_t* Bsrc = B + (long)(n0 + sRow) * ldb + sSl * 8;
  const long aStep = (long)128 * lda, bStep = (long)128 * ldb;

#define STAGE_A(b, h, kt) do { \
    const bf16_t* s_ = Asrc + (kt) * 64 + (h) * 32; \
    gll16(s_,         ASH(b, h) + tid * 8); \
    gll16(s_ + aStep, ASH(b, h) + 4096 + tid * 8); } while (0)
#define STAGE_B(b, h, kt) do { \
    const bf16_t* s_ = Bsrc + (kt) * 64 + (h) * 32; \
    gll16(s_,         BSH(b, h) + tid * 8); \
    gll16(s_ + bStep, BSH(b, h) + 4096 + tid * 8); } while (0)

  const int sw = (lh ^ ((lr >> 1) & 3)) * 8;
  const int aOff = (wr * 128 + lr) * 32 + sw;
  const int bOff = (wc * 64 + lr) * 32 + sw;

  f32x4 acc[8][4] = {};
  const int NT = K >> 6;

#define LGKM(n) do { \
    asm volatile("s_waitcnt lgkmcnt(" #n ")" ::: "memory"); \
    __builtin_amdgcn_sched_barrier(0); } while (0)
#define MFMA16(AS, BS, mo) do { \
    __builtin_amdgcn_s_setprio(1); \
    _Pragma("unroll") for (int m = 0; m < 4; ++m) \
    _Pragma("unroll") for (int n = 0; n < 4; ++n) \
      acc[m + (mo)][n] = __builtin_amdgcn_mfma_f32_16x16x32_bf16(AS[m], BS[n], acc[m + (mo)][n], 0, 0, 0); \
    __builtin_amdgcn_s_setprio(0); } while (0)

  STAGE_A(0, 0, 0); STAGE_B(0, 0, 0); STAGE_A(0, 1, 0); STAGE_B(0, 1, 0);
  asm volatile("s_waitcnt vmcnt(4)" ::: "memory");
  __builtin_amdgcn_s_barrier();

  bf16x8_t aA[4], aB[4], bA[4], bB[4];
#pragma unroll
  for (int n = 0; n < 4; ++n) bA[n] = *(const bf16x8_t*)(BSH(0, 0) + bOff + n * 512);
#pragma unroll
  for (int m = 0; m < 4; ++m) aA[m] = *(const bf16x8_t*)(ASH(0, 0) + aOff + m * 512);

  for (int t = 0; t < NT; ++t) {
    const int p = t & 1, q = p ^ 1;
    const bool pf = (t + 1 < NT);

#pragma unroll
    for (int m = 0; m < 4; ++m) aB[m] = *(const bf16x8_t*)(ASH(p, 0) + aOff + (m + 4) * 512);
    if (pf) STAGE_A(q, 0, t + 1);
    LGKM(4);
    MFMA16(aA, bA, 0);

    if (pf) {
      asm volatile("s_waitcnt vmcnt(2)" ::: "memory");
    } else {
      asm volatile("s_waitcnt vmcnt(0)" ::: "memory");
    }
    __builtin_amdgcn_sched_barrier(0);
    __builtin_amdgcn_s_barrier();
#pragma unroll
    for (int m = 0; m < 4; ++m) aA[m] = *(const bf16x8_t*)(ASH(p, 1) + aOff + m * 512);
#pragma unroll
    for (int n = 0; n < 4; ++n) bB[n] = *(const bf16x8_t*)(BSH(p, 1) + bOff + n * 512);
    if (pf) STAGE_B(q, 0, t + 1);
    LGKM(8);
    MFMA16(aB, bA, 4);

#pragma unroll
    for (int m = 0; m < 4; ++m) aB[m] = *(const bf16x8_t*)(ASH(p, 1) + aOff + (m + 4) * 512);
    if (pf) STAGE_A(q, 1, t + 1);
    LGKM(4);
    MFMA16(aA, bB, 0);

    if (pf) STAGE_B(q, 1, t + 1);
    asm volatile("s_waitcnt lgkmcnt(0)" ::: "memory");
    if (pf) {
      asm volatile("s_waitcnt vmcnt(4)" ::: "memory");
    }
    __builtin_amdgcn_sched_barrier(0);
    __builtin_amdgcn_s_barrier();
    if (pf) {
#pragma unroll
      for (int n = 0; n < 4; ++n) bA[n] = *(const bf16x8_t*)(BSH(q, 0) + bOff + n * 512);
#pragma unroll
      for (int m = 0; m < 4; ++m) aA[m] = *(const bf16x8_t*)(ASH(q, 0) + aOff + m * 512);
    }
    __builtin_amdgcn_sched_barrier(0);
    MFMA16(aB, bB, 4);
  }
#undef STAGE_A
#undef STAGE_B
#undef LGKM
#undef MFMA16

  bf16_t* Cb = C + (long)bz * sCb;
  const int rowb = m0 + wr * 128 + lh * 4;
  const int colb = n0 + wc * 64 + lr;
#pragma unroll
  for (int m = 0; m < 8; ++m)
#pragma unroll
    for (int n = 0; n < 4; ++n) {
      const f32x4 v = acc[m][n];
      const int cc = colb + n * 16;
#pragma unroll
      for (int r = 0; r < 4; ++r) {
        const int rr = rowb + m * 16 + r;
        Cb[(long)rr * ldc + cc] = (bf16_t)v[r];
      }
    }
#undef ASH
#undef BSH
}

// ---------------------------------------------------------------------------
// scores128 (R13): single K-pass, sigmoid, LDS-bounce coalesced write.
// ---------------------------------------------------------------------------
__global__ __launch_bounds__(256) void scores128(
    const bf16_t* __restrict__ kq, bf16_t* __restrict__ C,
    const float* __restrict__ biases) {
  const int orig = blockIdx.x + 16 * blockIdx.y + 256 * blockIdx.z;
  const int lid = (orig & 7) * 256 + (orig >> 3);
  const int bz = lid >> 8;
  const int rem = lid & 255;
  const int bx = rem & 15, by = rem >> 4;

  const bf16_t* A = kq + (long)bz * 2048 * 128;
  const bf16_t* B = A + 64;
  const float* a0 = biases + (long)bz * 2048;
  const int m0 = by * 128, n0 = bx * 128;

  __shared__ bf16_t SM[16384];
#define ASH(h) (&SM[(h) << 12])
#define BSH(h) (&SM[8192 + ((h) << 12)])

  const int tid = threadIdx.x;
  const int w = tid >> 6, l = tid & 63;
  const int wr = w >> 1, wc = w & 1;
  const int lr = l & 15, lh = l >> 4;

  const int sRow = tid >> 2;
  const int sSl = ((tid & 3) ^ ((tid >> 3) & 3)) * 8;
  const bf16_t* As = A + (long)(m0 + sRow) * 128 + sSl;
  const bf16_t* Bs = B + (long)(n0 + sRow) * 128 + sSl;
#pragma unroll
  for (int h = 0; h < 2; ++h) {
    gll16(As + h * 32, ASH(h) + tid * 8);
    gll16(As + h * 32 + 64 * 128, ASH(h) + 2048 + tid * 8);
    gll16(Bs + h * 32, BSH(h) + tid * 8);
    gll16(Bs + h * 32 + 64 * 128, BSH(h) + 2048 + tid * 8);
  }
  asm volatile("s_waitcnt vmcnt(0)" ::: "memory");
  __builtin_amdgcn_s_barrier();

  const int sw = (lh ^ ((lr >> 1) & 3)) * 8;
  const int aOff = (wr * 64 + lr) * 32 + sw;
  const int bOff = (wc * 64 + lr) * 32 + sw;

  f32x4 acc[4][4] = {};
#pragma unroll
  for (int h = 0; h < 2; ++h) {
    bf16x8_t aF[4], bF[4];
#pragma unroll
    for (int m = 0; m < 4; ++m) aF[m] = *(const bf16x8_t*)(ASH(h) + aOff + m * 512);
#pragma unroll
    for (int n = 0; n < 4; ++n) bF[n] = *(const bf16x8_t*)(BSH(h) + bOff + n * 512);
#pragma unroll
    for (int m = 0; m < 4; ++m)
#pragma unroll
      for (int n = 0; n < 4; ++n)
        acc[m][n] = __builtin_amdgcn_mfma_f32_16x16x32_bf16(aF[m], bF[n], acc[m][n], 0, 0, 0);
  }

  __builtin_amdgcn_s_barrier();
  {
    const int rowb = (wr << 6) + (lh << 2);
    const int colb = (wc << 6) + lr;
#pragma unroll
    for (int m = 0; m < 4; ++m)
#pragma unroll
      for (int n = 0; n < 4; ++n) {
        const f32x4 v = acc[m][n];
        const int cl = colb + (n << 4);
#pragma unroll
        for (int r = 0; r < 4; ++r) {
          const int rl = rowb + (m << 4) + r;
          const float zz = v[r] + a0[m0 + rl];
          SM[rl * 128 + (cl ^ (lh << 4))] =
              (bf16_t)__builtin_amdgcn_rcpf(1.0f + __expf(-zz));
        }
      }
    __syncthreads();
    bf16_t* Cb = C + (long)bz * 2048 * 2048;
    const int chunk = tid & 15, rsub = tid >> 4;
#pragma unroll
    for (int pp = 0; pp < 8; ++pp) {
      const int rl = pp * 16 + rsub;
      const int sc = chunk ^ (((rl >> 2) & 3) << 1);
      const bf16x8_t vv = *(const bf16x8_t*)&SM[rl * 128 + sc * 8];
      *(bf16x8_t*)&Cb[(long)(m0 + rl) * 2048 + n0 + chunk * 8] = vv;
    }
  }
#undef ASH
#undef BSH
}

// ---------------------------------------------------------------------------
// prep: blocks <4096 = cast x->bf16 + row-dot bias; blocks >=4096 = weight
// transposes (Wv, W1, Wk, Wq).
// ---------------------------------------------------------------------------
__global__ __launch_bounds__(256) void prep(
    const float* __restrict__ x, const float* __restrict__ Wb,
    const float* __restrict__ bb, bf16_t* __restrict__ x_bf,
    float* __restrict__ biases,
    const float* __restrict__ Wk, const float* __restrict__ Wq,
    const float* __restrict__ Wv, const float* __restrict__ W1,
    bf16_t* __restrict__ Wkqt, bf16_t* __restrict__ Wvt,
    bf16_t* __restrict__ W1t) {
  __shared__ float t[32][33];
  if (blockIdx.x < 4096) {
    const int r = blockIdx.x * 4 + (threadIdx.x >> 6);
    const int l = threadIdx.x & 63;
    const float* xr = x + (long)r * 1024;
    bf16_t* orow = x_bf + (long)r * 1024;
    float s = 0.f;
#pragma unroll
    for (int i = 0; i < 4; ++i) {
      const int off = l * 4 + i * 256;
      const float4 v = *(const float4*)(xr + off);
      const float4 w = *(const float4*)(Wb + off);
      s += v.x * w.x + v.y * w.y + v.z * w.z + v.w * w.w;
      bf16x4_t o;
      o[0] = (bf16_t)v.x; o[1] = (bf16_t)v.y; o[2] = (bf16_t)v.z; o[3] = (bf16_t)v.w;
      *(bf16x4_t*)(orow + off) = o;
    }
#pragma unroll
    for (int off = 1; off < 64; off <<= 1) s += __shfl_xor(s, off);
    if (l == 0) biases[r] = s + bb[0];
    return;
  }
  int b = blockIdx.x - 4096;
  const float* in;
  bf16_t* out;
  int R = 1024, C, c0, r0;
  if (b < 1024) {
    in = Wv; out = Wvt; C = 1024;
    c0 = (b & 31) * 32; r0 = (b >> 5) * 32;
  } else if (b < 2048) {
    b -= 1024; in = W1; out = W1t; C = 1024;
    c0 = (b & 31) * 32; r0 = (b >> 5) * 32;
  } else if (b < 2112) {
    b -= 2048; in = Wk; out = Wkqt; C = 64;
    c0 = (b & 1) * 32; r0 = (b >> 1) * 32;
  } else {
    b -= 2112; in = Wq; out = Wkqt + 64 * 1024; C = 64;
    c0 = (b & 1) * 32; r0 = (b >> 1) * 32;
  }
  const int tx = threadIdx.x & 31, ty = threadIdx.x >> 5;
#pragma unroll
  for (int i = 0; i < 4; ++i) {
    const int rl = ty * 4 + i;
    t[rl][tx] = in[(long)(r0 + rl) * C + c0 + tx];
  }
  __syncthreads();
#pragma unroll
  for (int i = 0; i < 4; ++i) {
    const int rl = ty * 4 + i;
    out[(long)(c0 + rl) * R + r0 + tx] = (bf16_t)t[tx][rl];
  }
}

// wave-per-row LayerNorm: res = bf16(LN(x+attn)*g+be)
__global__ __launch_bounds__(256) void ln1_kernel(
    const bf16_t* __restrict__ x, const bf16_t* __restrict__ attn,
    const float* __restrict__ g, const float* __restrict__ be,
    bf16_t* __restrict__ res) {
  const int w = threadIdx.x >> 6, l = threadIdx.x & 63;
  const long r = (long)blockIdx.x * 4 + w;
  const bf16_t* xr = x + r * 1024;
  const bf16_t* ar = attn + r * 1024;
  float y[16];
  float s = 0.f, ss = 0.f;
#pragma unroll
  for (int h = 0; h < 2; ++h) {
    const int base = h * 512 + l * 8;
    const bf16x8_t xv = *(const bf16x8_t*)(xr + base);
    const bf16x8_t av = *(const bf16x8_t*)(ar + base);
#pragma unroll
    for (int j = 0; j < 8; ++j) {
      const float yy = (float)xv[j] + (float)av[j];
      y[h * 8 + j] = yy;
      s += yy; ss += yy * yy;
    }
  }
#pragma unroll
  for (int off = 1; off < 64; off <<= 1) {
    s += __shfl_xor(s, off);
    ss += __shfl_xor(ss, off);
  }
  const float mean = s * (1.0f / 1024.0f);
  const float rs = rsqrtf(ss * (1.0f / 1024.0f) - mean * mean + 1e-5f);
  bf16_t* orow = res + r * 1024;
#pragma unroll
  for (int h = 0; h < 2; ++h) {
    const int base = h * 512 + l * 8;
    bf16x8_t o;
#pragma unroll
    for (int j = 0; j < 8; ++j)
      o[j] = (bf16_t)((y[h * 8 + j] - mean) * rs * g[base + j] + be[base + j]);
    *(bf16x8_t*)(orow + base) = o;
  }
}

// wave-per-row: out = LN(res + h), fp32 out
__global__ __launch_bounds__(256) void ln2_kernel(
    const bf16_t* __restrict__ res, const bf16_t* __restrict__ hh,
    float* __restrict__ out) {
  const int w = threadIdx.x >> 6, l = threadIdx.x & 63;
  const long r = (long)blockIdx.x * 4 + w;
  const bf16_t* rr = res + r * 1024;
  const bf16_t* hr = hh + r * 1024;
  float y[16];
  float s = 0.f, ss = 0.f;
#pragma unroll
  for (int h = 0; h < 2; ++h) {
    const int base = h * 512 + l * 8;
    const bf16x8_t rv = *(const bf16x8_t*)(rr + base);
    const bf16x8_t hv = *(const bf16x8_t*)(hr + base);
#pragma unroll
    for (int j = 0; j < 8; ++j) {
      const float yy = (float)rv[j] + (float)hv[j];
      y[h * 8 + j] = yy;
      s += yy; ss += yy * yy;
    }
  }
#pragma unroll
  for (int off = 1; off < 64; off <<= 1) {
    s += __shfl_xor(s, off);
    ss += __shfl_xor(ss, off);
  }
  const float mean = s * (1.0f / 1024.0f);
  const float rs = rsqrtf(ss * (1.0f / 1024.0f) - mean * mean + 1e-5f);
  float* orow = out + r * 1024;
#pragma unroll
  for (int h = 0; h < 2; ++h) {
    const int base = h * 512 + l * 8;
    float4 o1, o2;
    o1.x = (y[h * 8 + 0] - mean) * rs; o1.y = (y[h * 8 + 1] - mean) * rs;
    o1.z = (y[h * 8 + 2] - mean) * rs; o1.w = (y[h * 8 + 3] - mean) * rs;
    o2.x = (y[h * 8 + 4] - mean) * rs; o2.y = (y[h * 8 + 5] - mean) * rs;
    o2.z = (y[h * 8 + 6] - mean) * rs; o2.w = (y[h * 8 + 7] - mean) * rs;
    *(float4*)(orow + base) = o1;
    *(float4*)(orow + base + 4) = o2;
  }
}

// ---------------------------------------------------------------------------
extern "C" void kernel_launch(void* const* d_in, const int* in_sizes, int n_in,
                              void* d_out, int out_size, void* d_ws, size_t ws_size,
                              hipStream_t stream) {
  const float* x   = (const float*)d_in[0];
  const float* Wk  = (const float*)d_in[1];
  const float* bk  = (const float*)d_in[2];
  const float* Wq  = (const float*)d_in[3];
  const float* bq  = (const float*)d_in[4];
  const float* Wv  = (const float*)d_in[5];
  const float* bv  = (const float*)d_in[6];
  const float* Wb  = (const float*)d_in[7];
  const float* bb  = (const float*)d_in[8];
  const float* W1  = (const float*)d_in[9];
  const float* b1  = (const float*)d_in[10];
  const float* g1  = (const float*)d_in[11];
  const float* be1 = (const float*)d_in[12];
  float* out = (float*)d_out;

  char* ws = (char*)d_ws;
  bf16_t* x_bf    = (bf16_t*)(ws + 0);           //  32 MB  [16384][1024]
  bf16_t* vt_bf   = (bf16_t*)(ws + 33554432);    //  32 MB  V^T [1024][16384]
  bf16_t* kq_bf   = (bf16_t*)(ws + 67108864);    //   4 MB  [16384][128]
  bf16_t* Wkqt    = (bf16_t*)(ws + 71303168);    // 256 KB  [128][1024]
  bf16_t* Wvt     = (bf16_t*)(ws + 71565312);    //   2 MB
  bf16_t* W1t     = (bf16_t*)(ws + 73662464);    //   2 MB
  float*  biases  = (float*) (ws + 75759616);    //  64 KB
  bf16_t* scores  = (bf16_t*)(ws + 75825152);    //  64 MB  [8][2048][2048]
  bf16_t* attn_bf = (bf16_t*)(ws + 142934016);   //  32 MB  [8][2048][1024]
  bf16_t* res_bf  = (bf16_t*)(ws + 176488448);   //  32 MB
  bf16_t* h_bf    = attn_bf;                     // alias: attn dead after ln1

  // cast+bias+transposes in one launch
  prep<<<6272, 256, 0, stream>>>(x, Wb, bb, x_bf, biases,
                                 Wk, Wq, Wv, W1, Wkqt, Wvt, W1t);

  // VT (512 blocks) + KQ (128 blocks) in ONE launch — independent work
  vt_kq<<<640, 512, 0, stream>>>(Wvt, x_bf, vt_bf, bv, Wkqt, kq_bf, bk, bq);

  // scores = sigmoid(keys.queries^T + bias_i)
  scores128<<<dim3(16, 16, 8), 256, 0, stream>>>(kq_bf, scores, biases);

  // attn = scores @ V
  gemm256p<3><<<dim3(4, 8, 8), 512, 0, stream>>>(
      scores, vt_bf, attn_bf, 2048, 2048, 16384, 1024,
      2048L * 2048, 2048, 2048L * 1024, nullptr);

  // res = bf16(LN(x+attn)*g1+be1)
  ln1_kernel<<<4096, 256, 0, stream>>>(x_bf, attn_bf, g1, be1, res_bf);

  // h = relu(res @ W1 + b1)
  gemm128n<4, 0><<<dim3(8, 64), 512, 0, stream>>>(
      res_bf, W1t, h_bf, 1024, 1024, 1024, 1024, b1);

  // out = LN(res + h)
  ln2_kernel<<<4096, 256, 0, stream>>>(res_bf, h_bf, out);
}